// Round 7
// baseline (450.236 us; speedup 1.0000x reference)
//
#include <hip/hip_runtime.h>

// Swin shifted-window attention, MI355X gfx950.
// f16 MFMA (16x16x32), fp32 accumulate + fp32 softmax.
// k_pre (gather+cvt) -> k_qkv (persistent 8-tile GEMM) -> k_attn -> k_out (persistent 4-tile GEMM).
// R6 = R5 with the nontemporal-store type fix (clang ext-vector, not HIP float4).
// XCD-chunk swizzle on persistent grids + NT stores for all streaming outputs.
// d_out doubles as q|k f16 buffer until k_out overwrites it (fp32).
// ws: [0,64MiB) xg (later reused as ao); [64,128MiB) vt.

using f16   = _Float16;
using f16x8 = __attribute__((ext_vector_type(8))) _Float16;
using f16x4 = __attribute__((ext_vector_type(4))) _Float16;
using f32x4 = __attribute__((ext_vector_type(4))) float;

#define MFMA16(a, b, c) __builtin_amdgcn_mfma_f32_16x16x32_f16((a), (b), (c), 0, 0, 0)
#define SCHEDBAR() __builtin_amdgcn_sched_barrier(0)
#define VMCNT(N) asm volatile("s_waitcnt vmcnt(" #N ")" ::: "memory")
#define LGKM0()  asm volatile("s_waitcnt lgkmcnt(0)" ::: "memory")
#define BAR()    __builtin_amdgcn_s_barrier()

static constexpr int QK_HALF = 65536 * 512;

typedef const __attribute__((address_space(1))) unsigned int* gp_t;
typedef __attribute__((address_space(3))) unsigned int* sp_t;
__device__ __forceinline__ void gl_lds16(const f16* g, f16* s) {
  __builtin_amdgcn_global_load_lds((gp_t)g, (sp_t)s, 16, 0, 0);
}

__device__ __forceinline__ void nts8(f16x8 v, f16* p) {
  __builtin_nontemporal_store(v, (f16x8*)p);
}
__device__ __forceinline__ void nts4f(f32x4 v, float* p) {
  __builtin_nontemporal_store(v, (f32x4*)p);
}
__device__ __forceinline__ void nts4h(f16x4 v, f16* p) {
  __builtin_nontemporal_store(v, (f16x4*)p);
}

__device__ __forceinline__ int tok2patch(int t) {
  int b = t >> 12, rem = t & 4095;
  int widx = rem >> 6, s = rem & 63;
  int pr = (((widx >> 3) << 3) + (s >> 3) + 4) & 63;
  int pc = (((widx & 7) << 3) + (s & 7) + 4) & 63;
  return ((b << 12) | (pr << 6) | pc) << 9;
}

__device__ __forceinline__ f16x8 cvt8(float4 a, float4 b) {
  f16x8 h = { (f16)a.x, (f16)a.y, (f16)a.z, (f16)a.w,
              (f16)b.x, (f16)b.y, (f16)b.z, (f16)b.w };
  return h;
}

// ---------------------------------------------------------------------------
// Kernel 0: gather (roll -4 + window partition) + fp32->f16.
// ---------------------------------------------------------------------------
__global__ __launch_bounds__(256) void k_pre(const float* __restrict__ x,
                                             f16* __restrict__ xg) {
  const int t = blockIdx.x * 16 + (threadIdx.x >> 4);
  const int i = threadIdx.x & 15;
  const float4* src = (const float4*)(x + tok2patch(t));
  f16* dst = xg + t * 512;
#pragma unroll
  for (int j = 0; j < 8; ++j) {
    float4 v = src[i + j * 16];
    f16x4 h = { (f16)v.x, (f16)v.y, (f16)v.z, (f16)v.w };
    nts4h(h, dst + (i + j * 16) * 4);
  }
}

// ---------------------------------------------------------------------------
// Persistent GEMM core: 128x128 tiles, BK=32, flat K-loop across tiles.
// Per iter u: [issue A-DMA(u+1)] [ds_read frags(u)] [16 MFMA]
//             [VMCNT(2); WRITEB(u+1)] [LOADB(u+2); VMCNT(4)] [lgkm0; BAR]
// ---------------------------------------------------------------------------

// Kernel 1: QKV projection. 768 blocks x 8 tiles (bn-fast over 512x12 grid).
__global__ __launch_bounds__(256, 3) void k_qkv(const f16* __restrict__ xg,
                                                const float* __restrict__ wq,
                                                const float* __restrict__ bq,
                                                f16* __restrict__ qk,
                                                f16* __restrict__ vt) {
  __shared__ __align__(16) char smem[51200];  // A0 A1 B0 B1 (8KB each) + Cw 18KB
  f16* const A0 = (f16*)smem;
  f16* const A1 = (f16*)(smem + 8192);
  f16* const B0 = (f16*)(smem + 16384);
  f16* const B1 = (f16*)(smem + 24576);

  const int tid = threadIdx.x;
  const int lane = tid & 63, wave = tid >> 6;
  const int jlo = lane & 15, g = lane >> 4;
  const int wrow = (wave >> 1) * 64, wcol = (wave & 1) * 64;

  // XCD chunking: ~96 consecutive blocks per XCD -> shared A-panels L2-resident
  const int blk = blockIdx.x;                      // 768
  const int swz = (blk & 7) * 96 + (blk >> 3);
  const int tile0 = swz * 8;
  constexpr int NU = 8 * 16;  // 8 tiles x 16 K-steps

  const int arow = wave * 32 + (lane >> 2);
  const int aq = (lane & 3) ^ ((lane >> 3) & 3);  // pre-swizzled global chunk
  const int nl = tid >> 1, kh = (tid & 1) * 16;
  const int bsw = (nl >> 1) & 3, bc0 = (tid & 1) * 2;

  float4 rb[4];
  f32x4 acc[4][4] = {};

  {  // prologue: stage tile0/k0, preload B(u=1)
    const int bm = tile0 / 12, bn = tile0 % 12;
    const f16* as = xg + (bm * 128 + arow) * 512 + aq * 8;
    gl_lds16(as, A0 + wave * 1024);
    gl_lds16(as + 16 * 512, A0 + wave * 1024 + 512);
    const float* bs = wq + (bn * 128 + nl) * 512 + kh;
    rb[0] = *(const float4*)(bs);
    rb[1] = *(const float4*)(bs + 4);
    rb[2] = *(const float4*)(bs + 8);
    rb[3] = *(const float4*)(bs + 12);
    SCHEDBAR();
    VMCNT(0);
    *(f16x8*)(B0 + nl * 32 + ((bc0 ^ bsw) * 8))       = cvt8(rb[0], rb[1]);
    *(f16x8*)(B0 + nl * 32 + (((bc0 + 1) ^ bsw) * 8)) = cvt8(rb[2], rb[3]);
    rb[0] = *(const float4*)(bs + 32);
    rb[1] = *(const float4*)(bs + 36);
    rb[2] = *(const float4*)(bs + 40);
    rb[3] = *(const float4*)(bs + 44);
    SCHEDBAR();
    LGKM0();
    BAR();
  }

#pragma unroll 1
  for (int u = 0; u < NU; ++u) {
    f16* const Ac = (u & 1) ? A1 : A0;
    f16* const Bc = (u & 1) ? B1 : B0;
    f16* const An = (u & 1) ? A0 : A1;
    f16* const Bn = (u & 1) ? B0 : B1;

    if (u + 1 < NU) {
      const int t1 = tile0 + ((u + 1) >> 4);
      const int k1 = ((u + 1) & 15) * 32;
      const f16* as = xg + ((t1 / 12) * 128 + arow) * 512 + k1 + aq * 8;
      gl_lds16(as, An + wave * 1024);
      gl_lds16(as + 16 * 512, An + wave * 1024 + 512);
    }
    SCHEDBAR();

    f16x8 af[4], bf[4];
#pragma unroll
    for (int mt = 0; mt < 4; ++mt) {
      const int m = wrow + mt * 16 + jlo;
      af[mt] = *(const f16x8*)(Ac + m * 32 + ((g ^ ((m >> 1) & 3)) * 8));
    }
#pragma unroll
    for (int nt = 0; nt < 4; ++nt) {
      const int n = wcol + nt * 16 + jlo;
      bf[nt] = *(const f16x8*)(Bc + n * 32 + ((g ^ ((n >> 1) & 3)) * 8));
    }
    __builtin_amdgcn_s_setprio(1);
#pragma unroll
    for (int mt = 0; mt < 4; ++mt)
#pragma unroll
      for (int nt = 0; nt < 4; ++nt)
        acc[mt][nt] = MFMA16(af[mt], bf[nt], acc[mt][nt]);
    __builtin_amdgcn_s_setprio(0);

    if (u + 1 < NU) {
      VMCNT(2);
      *(f16x8*)(Bn + nl * 32 + ((bc0 ^ bsw) * 8))       = cvt8(rb[0], rb[1]);
      *(f16x8*)(Bn + nl * 32 + (((bc0 + 1) ^ bsw) * 8)) = cvt8(rb[2], rb[3]);
    }
    SCHEDBAR();
    if (u + 2 < NU) {
      const int t2 = tile0 + ((u + 2) >> 4);
      const int k2 = ((u + 2) & 15) * 32;
      const float* bs = wq + ((t2 % 12) * 128 + nl) * 512 + k2 + kh;
      rb[0] = *(const float4*)(bs);
      rb[1] = *(const float4*)(bs + 4);
      rb[2] = *(const float4*)(bs + 8);
      rb[3] = *(const float4*)(bs + 12);
      SCHEDBAR();
      VMCNT(4);
    } else {
      VMCNT(0);
    }
    LGKM0();
    BAR();

    if ((u & 15) == 15) {  // per-tile epilogue (per-wave Cw, no extra barrier)
      const int tt = tile0 + (u >> 4);
      const int bm = tt / 12, bn = tt % 12;
      float bias[4];
#pragma unroll
      for (int nt = 0; nt < 4; ++nt) bias[nt] = bq[bn * 128 + wcol + nt * 16 + jlo];
      f16* Cw = (f16*)(smem + 32768) + wave * 2304;  // 32 x 72
      if (bn < 8) {  // q or k: row-major token rows, 2 half-passes
        f16* gb = (bn < 4) ? (qk + bn * 128 + wcol)
                           : (qk + QK_HALF + (bn - 4) * 128 + wcol);
#pragma unroll
        for (int p = 0; p < 2; ++p) {
#pragma unroll
          for (int m2 = 0; m2 < 2; ++m2) {
            const int mt = p * 2 + m2;
#pragma unroll
            for (int nt = 0; nt < 4; ++nt)
#pragma unroll
              for (int r = 0; r < 4; ++r)
                Cw[(m2 * 16 + g * 4 + r) * 72 + nt * 16 + jlo] =
                    (f16)(acc[mt][nt][r] + bias[nt]);
          }
          LGKM0();
#pragma unroll
          for (int c = 0; c < 4; ++c) {  // 8 lanes/row -> 128B contiguous
            const int lr = c * 8 + (lane >> 3);
            const int trow = bm * 128 + wrow + p * 32 + lr;
            nts8(*(const f16x8*)(Cw + lr * 72 + (lane & 7) * 8),
                 gb + trow * 512 + (lane & 7) * 8);
          }
        }
      } else {  // v: transposed per (window, head) -> vt[w][h][d][s]
        const int nb = (bn - 8) * 128 + wcol;
        const int w = (bm * 128 + wrow) >> 6;
#pragma unroll
        for (int p = 0; p < 2; ++p) {
#pragma unroll
          for (int n2 = 0; n2 < 2; ++n2) {
            const int nt = p * 2 + n2;
#pragma unroll
            for (int mt = 0; mt < 4; ++mt) {
              f16x4 pk = { (f16)(acc[mt][nt][0] + bias[nt]), (f16)(acc[mt][nt][1] + bias[nt]),
                           (f16)(acc[mt][nt][2] + bias[nt]), (f16)(acc[mt][nt][3] + bias[nt]) };
              *(f16x4*)(Cw + (n2 * 16 + jlo) * 72 + mt * 16 + g * 4) = pk;
            }
          }
          LGKM0();
#pragma unroll
          for (int c = 0; c < 4; ++c) {
            const int cl = c * 8 + (lane >> 3);  // local col 0..31
            const int n = nb + p * 32 + cl;
            const int h = n >> 5, d = n & 31;
            nts8(*(const f16x8*)(Cw + cl * 72 + (lane & 7) * 8),
                 vt + ((w * 16 + h) * 32 + d) * 64 + (lane & 7) * 8);
          }
        }
      }
#pragma unroll
      for (int mt = 0; mt < 4; ++mt)
#pragma unroll
        for (int nt = 0; nt < 4; ++nt)
          acc[mt][nt] = (f32x4){0.f, 0.f, 0.f, 0.f};
    }
  }
}

// ---------------------------------------------------------------------------
// Kernel 2: per-window attention (NT final stores).
// ---------------------------------------------------------------------------
__global__ __launch_bounds__(256) void k_attn(const f16* __restrict__ qk,
                                              const f16* __restrict__ vt,
                                              f16* __restrict__ ao) {
  __shared__ f16 P[4][64 * 72];
  const int w = blockIdx.x;
  const int widx = w & 63;
  const bool er = (widx >> 3) == 7;
  const bool ec = (widx & 7) == 7;
  const int tid = threadIdx.x;
  const int lane = tid & 63, wave = tid >> 6;
  const int jlo = lane & 15, g = lane >> 4;
  const int tb = w * 64;
  f16* Pw = P[wave];
  const float scale = 0.17677669529663687f;

#pragma unroll 1
  for (int hh = 0; hh < 4; ++hh) {
    const int h = wave * 4 + hh;
    f16x8 qa[4], kb[4];
#pragma unroll
    for (int mt = 0; mt < 4; ++mt)
      qa[mt] = *(const f16x8*)(qk + (tb + mt * 16 + jlo) * 512 + h * 32 + g * 8);
#pragma unroll
    for (int nt = 0; nt < 4; ++nt)
      kb[nt] = *(const f16x8*)(qk + QK_HALF + (tb + nt * 16 + jlo) * 512 + h * 32 + g * 8);
    f32x4 sc[4][4] = {};
#pragma unroll
    for (int mt = 0; mt < 4; ++mt)
#pragma unroll
      for (int nt = 0; nt < 4; ++nt)
        sc[mt][nt] = MFMA16(qa[mt], kb[nt], sc[mt][nt]);

    int gj[4];
#pragma unroll
    for (int nt = 0; nt < 4; ++nt) {
      int j = nt * 16 + jlo;
      gj[nt] = ((er && ((j >> 3) >= 4)) ? 2 : 0) | ((ec && ((j & 7) >= 4)) ? 1 : 0);
    }
    float rinv[4][4];
#pragma unroll
    for (int mt = 0; mt < 4; ++mt) {
#pragma unroll
      for (int r = 0; r < 4; ++r) {
        const int i = mt * 16 + g * 4 + r;
        const int gi = ((er && ((i >> 3) >= 4)) ? 2 : 0) | ((ec && ((i & 7) >= 4)) ? 1 : 0);
        float v0 = (gi == gj[0]) ? sc[mt][0][r] * scale : -1e9f;
        float v1 = (gi == gj[1]) ? sc[mt][1][r] * scale : -1e9f;
        float v2 = (gi == gj[2]) ? sc[mt][2][r] * scale : -1e9f;
        float v3 = (gi == gj[3]) ? sc[mt][3][r] * scale : -1e9f;
        float m = fmaxf(fmaxf(v0, v1), fmaxf(v2, v3));
        m = fmaxf(m, __shfl_xor(m, 1));
        m = fmaxf(m, __shfl_xor(m, 2));
        m = fmaxf(m, __shfl_xor(m, 4));
        m = fmaxf(m, __shfl_xor(m, 8));
        float p0 = __expf(v0 - m), p1 = __expf(v1 - m);
        float p2 = __expf(v2 - m), p3 = __expf(v3 - m);
        float s = p0 + p1 + p2 + p3;
        s += __shfl_xor(s, 1);
        s += __shfl_xor(s, 2);
        s += __shfl_xor(s, 4);
        s += __shfl_xor(s, 8);
        rinv[mt][r] = 1.0f / s;
        sc[mt][0][r] = p0; sc[mt][1][r] = p1; sc[mt][2][r] = p2; sc[mt][3][r] = p3;
      }
    }
#pragma unroll
    for (int mt = 0; mt < 4; ++mt)
#pragma unroll
      for (int nt = 0; nt < 4; ++nt)
#pragma unroll
        for (int r = 0; r < 4; ++r)
          Pw[(mt * 16 + g * 4 + r) * 72 + nt * 16 + jlo] = (f16)sc[mt][nt][r];
    asm volatile("s_waitcnt lgkmcnt(0)" ::: "memory");

    f32x4 o[4][2] = {};
#pragma unroll
    for (int ks = 0; ks < 2; ++ks) {
      f16x8 pa[4], vb[2];
#pragma unroll
      for (int mt = 0; mt < 4; ++mt)
        pa[mt] = *(const f16x8*)((const char*)Pw + (mt * 16 + jlo) * 144 + ks * 64 + g * 16);
#pragma unroll
      for (int nt = 0; nt < 2; ++nt)
        vb[nt] = *(const f16x8*)(vt + ((w * 16 + h) * 32 + nt * 16 + jlo) * 64 + ks * 32 + g * 8);
#pragma unroll
      for (int mt = 0; mt < 4; ++mt)
#pragma unroll
        for (int nt = 0; nt < 2; ++nt)
          o[mt][nt] = MFMA16(pa[mt], vb[nt], o[mt][nt]);
    }
#pragma unroll
    for (int mt = 0; mt < 4; ++mt)
#pragma unroll
      for (int nt = 0; nt < 2; ++nt)
#pragma unroll
        for (int r = 0; r < 4; ++r)
          Pw[(mt * 16 + g * 4 + r) * 40 + nt * 16 + jlo] =
              (f16)(o[mt][nt][r] * rinv[mt][r]);
    f16* arow = ao + (tb + lane) * 512 + h * 32;
#pragma unroll
    for (int c = 0; c < 4; ++c)
      nts8(*(const f16x8*)(Pw + lane * 40 + c * 8), arow + c * 8);
  }
}

// ---------------------------------------------------------------------------
// Kernel 3: output projection + window-merge/roll scatter (fp32 out, NT).
// 512 blocks x 4 tiles; XCD-chunked bm.
// ---------------------------------------------------------------------------
__global__ __launch_bounds__(256, 2) void k_out(const f16* __restrict__ ao,
                                                const float* __restrict__ wo,
                                                const float* __restrict__ bo,
                                                float* __restrict__ out) {
  __shared__ __align__(16) char smem[67584];  // 32KB loop bufs + 34816B Cw(f32)
  f16* const A0 = (f16*)smem;
  f16* const A1 = (f16*)(smem + 8192);
  f16* const B0 = (f16*)(smem + 16384);
  f16* const B1 = (f16*)(smem + 24576);

  const int tid = threadIdx.x;
  const int lane = tid & 63, wave = tid >> 6;
  const int jlo = lane & 15, g = lane >> 4;
  const int wrow = (wave >> 1) * 64, wcol = (wave & 1) * 64;

  const int blk = blockIdx.x;  // 512
  const int bm = (blk & 7) * 64 + (blk >> 3);  // XCD chunking
  constexpr int NU = 4 * 16;

  const int arow = wave * 32 + (lane >> 2);
  const int aq = (lane & 3) ^ ((lane >> 3) & 3);
  const f16* const abase = ao + (bm * 128 + arow) * 512 + aq * 8;
  const int nl = tid >> 1, kh = (tid & 1) * 16;
  const int bsw = (nl >> 1) & 3, bc0 = (tid & 1) * 2;

  float4 rb[4];
  f32x4 acc[4][4] = {};

  {  // prologue
    gl_lds16(abase, A0 + wave * 1024);
    gl_lds16(abase + 16 * 512, A0 + wave * 1024 + 512);
    const float* bs = wo + nl * 512 + kh;  // bn=0
    rb[0] = *(const float4*)(bs);
    rb[1] = *(const float4*)(bs + 4);
    rb[2] = *(const float4*)(bs + 8);
    rb[3] = *(const float4*)(bs + 12);
    SCHEDBAR();
    VMCNT(0);
    *(f16x8*)(B0 + nl * 32 + ((bc0 ^ bsw) * 8))       = cvt8(rb[0], rb[1]);
    *(f16x8*)(B0 + nl * 32 + (((bc0 + 1) ^ bsw) * 8)) = cvt8(rb[2], rb[3]);
    rb[0] = *(const float4*)(bs + 32);
    rb[1] = *(const float4*)(bs + 36);
    rb[2] = *(const float4*)(bs + 40);
    rb[3] = *(const float4*)(bs + 44);
    SCHEDBAR();
    LGKM0();
    BAR();
  }

#pragma unroll 1
  for (int u = 0; u < NU; ++u) {
    f16* const Ac = (u & 1) ? A1 : A0;
    f16* const Bc = (u & 1) ? B1 : B0;
    f16* const An = (u & 1) ? A0 : A1;
    f16* const Bn = (u & 1) ? B0 : B1;

    if (u + 1 < NU) {
      const int k1 = ((u + 1) & 15) * 32;
      gl_lds16(abase + k1, An + wave * 1024);
      gl_lds16(abase + k1 + 16 * 512, An + wave * 1024 + 512);
    }
    SCHEDBAR();

    f16x8 af[4], bf[4];
#pragma unroll
    for (int mt = 0; mt < 4; ++mt) {
      const int m = wrow + mt * 16 + jlo;
      af[mt] = *(const f16x8*)(Ac + m * 32 + ((g ^ ((m >> 1) & 3)) * 8));
    }
#pragma unroll
    for (int nt = 0; nt < 4; ++nt) {
      const int n = wcol + nt * 16 + jlo;
      bf[nt] = *(const f16x8*)(Bc + n * 32 + ((g ^ ((n >> 1) & 3)) * 8));
    }
    __builtin_amdgcn_s_setprio(1);
#pragma unroll
    for (int mt = 0; mt < 4; ++mt)
#pragma unroll
      for (int nt = 0; nt < 4; ++nt)
        acc[mt][nt] = MFMA16(af[mt], bf[nt], acc[mt][nt]);
    __builtin_amdgcn_s_setprio(0);

    if (u + 1 < NU) {
      VMCNT(2);
      *(f16x8*)(Bn + nl * 32 + ((bc0 ^ bsw) * 8))       = cvt8(rb[0], rb[1]);
      *(f16x8*)(Bn + nl * 32 + (((bc0 + 1) ^ bsw) * 8)) = cvt8(rb[2], rb[3]);
    }
    SCHEDBAR();
    if (u + 2 < NU) {
      const int bn2 = (u + 2) >> 4;
      const int k2 = ((u + 2) & 15) * 32;
      const float* bs = wo + (bn2 * 128 + nl) * 512 + k2 + kh;
      rb[0] = *(const float4*)(bs);
      rb[1] = *(const float4*)(bs + 4);
      rb[2] = *(const float4*)(bs + 8);
      rb[3] = *(const float4*)(bs + 12);
      SCHEDBAR();
      VMCNT(4);
    } else {
      VMCNT(0);
    }
    LGKM0();
    BAR();

    if ((u & 15) == 15) {  // epilogue: fp32 scatter via tok2patch, 2 half-passes
      const int bn = u >> 4;
      float bias[4];
#pragma unroll
      for (int nt = 0; nt < 4; ++nt) bias[nt] = bo[bn * 128 + wcol + nt * 16 + jlo];
      float* Cw = (float*)(smem + 32768) + wave * (32 * 68);
#pragma unroll
      for (int p = 0; p < 2; ++p) {
#pragma unroll
        for (int m2 = 0; m2 < 2; ++m2) {
          const int mt = p * 2 + m2;
#pragma unroll
          for (int nt = 0; nt < 4; ++nt)
#pragma unroll
            for (int r = 0; r < 4; ++r)
              Cw[(m2 * 16 + g * 4 + r) * 68 + nt * 16 + jlo] = acc[mt][nt][r] + bias[nt];
        }
        LGKM0();
#pragma unroll
        for (int c = 0; c < 8; ++c) {  // 16 lanes/row -> 256B contiguous
          const int lr = c * 4 + (lane >> 4);
          const int trow = bm * 128 + wrow + p * 32 + lr;
          nts4f(*(const f32x4*)(Cw + lr * 68 + (lane & 15) * 4),
                out + tok2patch(trow) + bn * 128 + wcol + (lane & 15) * 4);
        }
      }
#pragma unroll
      for (int mt = 0; mt < 4; ++mt)
#pragma unroll
        for (int nt = 0; nt < 4; ++nt)
          acc[mt][nt] = (f32x4){0.f, 0.f, 0.f, 0.f};
    }
  }
}

extern "C" void kernel_launch(void* const* d_in, const int* in_sizes, int n_in,
                              void* d_out, int out_size, void* d_ws, size_t ws_size,
                              hipStream_t stream) {
  const float* x  = (const float*)d_in[0];
  const float* wq = (const float*)d_in[1];
  const float* bq = (const float*)d_in[2];
  const float* wo = (const float*)d_in[3];
  const float* bo = (const float*)d_in[4];
  float* out = (float*)d_out;

  f16* qk = (f16*)d_out;                        // q|k overlay (128 MiB)
  f16* xg = (f16*)d_ws;                         // gathered f16 x (64 MiB)
  f16* vt = (f16*)((char*)d_ws + (64u << 20));  // V transposed (64 MiB)
  f16* ao = xg;                                 // reuse after k_qkv

  k_pre<<<dim3(4096), 256, 0, stream>>>(x, xg);
  k_qkv<<<dim3(768), 256, 0, stream>>>(xg, wq, bq, qk, vt);
  k_attn<<<dim3(1024), 256, 0, stream>>>(qk, vt, ao);
  k_out<<<dim3(512), 256, 0, stream>>>(ao, wo, bo, out);
}

// Round 8
// 377.442 us; speedup vs baseline: 1.1929x; 1.1929x over previous
//
#include <hip/hip_runtime.h>

// Swin shifted-window attention, MI355X gfx950.  R7: A-in-registers GEMMs.
// k_qkv: 256 blocks x 512 thr; A panel (256 tok x 512) gathered from x once into
//   af[2][16] regs; B (wqkv) streamed via 8KB LDS dbuf; 12 bn-tiles/block.
// k_attn: per-window attention (normal stores).
// k_out: same structure, A=ao, 4 bn-tiles, NT stores only on final out.
// d_out holds q|k f16 overlay until k_out overwrites it (fp32).
// ws: [0,64MiB) ao; [64,128MiB) vt.

using f16   = _Float16;
using f16x8 = __attribute__((ext_vector_type(8))) _Float16;
using f16x4 = __attribute__((ext_vector_type(4))) _Float16;
using f32x4 = __attribute__((ext_vector_type(4))) float;

#define MFMA16(a, b, c) __builtin_amdgcn_mfma_f32_16x16x32_f16((a), (b), (c), 0, 0, 0)
#define SCHEDBAR() __builtin_amdgcn_sched_barrier(0)
#define VMCNT0() asm volatile("s_waitcnt vmcnt(0)" ::: "memory")
#define LGKM0()  asm volatile("s_waitcnt lgkmcnt(0)" ::: "memory")
#define BAR()    __builtin_amdgcn_s_barrier()

static constexpr int QK_HALF = 65536 * 512;

__device__ __forceinline__ void nts4f(f32x4 v, float* p) {
  __builtin_nontemporal_store(v, (f32x4*)p);
}

__device__ __forceinline__ int tok2patch(int t) {
  int b = t >> 12, rem = t & 4095;
  int widx = rem >> 6, s = rem & 63;
  int pr = (((widx >> 3) << 3) + (s >> 3) + 4) & 63;
  int pc = (((widx & 7) << 3) + (s & 7) + 4) & 63;
  return ((b << 12) | (pr << 6) | pc) << 9;
}

__device__ __forceinline__ f16x8 cvt8(float4 a, float4 b) {
  f16x8 h = { (f16)a.x, (f16)a.y, (f16)a.z, (f16)a.w,
              (f16)b.x, (f16)b.y, (f16)b.z, (f16)b.w };
  return h;
}

// ---------------------------------------------------------------------------
// Kernel 1: QKV projection, A-in-registers.
// Wave w owns output rows [bm*256 + w*32, +32) x all 128 cols of each bn tile.
// Per K-step: 8 ds_read_b128 (B frags) + 16 MFMA; B(u+1) committed from regs,
// B(u+2) reg-prefetched.  Single barrier per step.
// ---------------------------------------------------------------------------
__global__ __launch_bounds__(512, 2) void k_qkv(const float* __restrict__ x,
                                                const float* __restrict__ wq,
                                                const float* __restrict__ bq,
                                                f16* __restrict__ qk,
                                                f16* __restrict__ vt) {
  __shared__ __align__(16) char smem[86016];  // B0|B1 8KB each + 8x8704B Cw
  f16* const B0 = (f16*)smem;
  f16* const B1 = (f16*)(smem + 8192);

  const int tid = threadIdx.x;
  const int lane = tid & 63, wave = tid >> 6;
  const int jlo = lane & 15, g = lane >> 4;
  const int bm = blockIdx.x;  // 256 blocks, one 256-token panel each

  const int nl = tid >> 2, kq = tid & 3;           // B staging: row nl, k-quarter
  const int bslot = (kq ^ ((nl >> 1) & 3)) * 8;    // swizzled 16B slot

  // ---- A panel -> registers (gather + cvt), af[mt][ks] ----
  const int r0 = tok2patch(bm * 256 + wave * 32 + jlo);
  const int r1 = tok2patch(bm * 256 + wave * 32 + 16 + jlo);
  f16x8 af[2][16];
#pragma unroll
  for (int kg = 0; kg < 4; ++kg) {
    float4 t0[4][2], t1[4][2];
#pragma unroll
    for (int k4 = 0; k4 < 4; ++k4) {
      const int ko = (kg * 4 + k4) * 32 + g * 8;
      t0[k4][0] = *(const float4*)(x + r0 + ko);
      t0[k4][1] = *(const float4*)(x + r0 + ko + 4);
      t1[k4][0] = *(const float4*)(x + r1 + ko);
      t1[k4][1] = *(const float4*)(x + r1 + ko + 4);
    }
#pragma unroll
    for (int k4 = 0; k4 < 4; ++k4) {
      af[0][kg * 4 + k4] = cvt8(t0[k4][0], t0[k4][1]);
      af[1][kg * 4 + k4] = cvt8(t1[k4][0], t1[k4][1]);
    }
    SCHEDBAR();
  }

  f32x4 acc[2][8] = {};
  float4 rb[2];
#define LOADB(U2)                                                         \
  do {                                                                    \
    const int bn2_ = (U2) >> 4, k2_ = ((U2) & 15) * 32;                   \
    const float* bs_ = wq + (bn2_ * 128 + nl) * 512 + k2_ + kq * 8;       \
    rb[0] = *(const float4*)(bs_); rb[1] = *(const float4*)(bs_ + 4);     \
  } while (0)
#define WRITEB(Bp) do { *(f16x8*)((Bp) + nl * 32 + bslot) = cvt8(rb[0], rb[1]); } while (0)

  // prologue
  LOADB(0);
  SCHEDBAR();
  VMCNT0();
  WRITEB(B0);
  LOADB(1);
  LGKM0();
  BAR();

#pragma unroll 1
  for (int bn = 0; bn < 12; ++bn) {
    f16* const Cw = (f16*)(smem + 16384 + wave * 8704);
#pragma unroll
    for (int ks = 0; ks < 16; ++ks) {
      const int u = bn * 16 + ks;
      f16* const Bc = (u & 1) ? B1 : B0;
      f16* const Bn = (u & 1) ? B0 : B1;
      f16x8 bf[8];
#pragma unroll
      for (int nt = 0; nt < 8; ++nt) {
        const int n = nt * 16 + jlo;
        bf[nt] = *(const f16x8*)(Bc + n * 32 + ((g ^ ((n >> 1) & 3)) * 8));
      }
      __builtin_amdgcn_s_setprio(1);
#pragma unroll
      for (int mt = 0; mt < 2; ++mt)
#pragma unroll
        for (int nt = 0; nt < 8; ++nt)
          acc[mt][nt] = MFMA16(af[mt][ks], bf[nt], acc[mt][nt]);
      __builtin_amdgcn_s_setprio(0);
      VMCNT0();  // rb(u+1) landed (issued one step ago)
      if (u + 1 < 192) WRITEB(Bn);
      SCHEDBAR();
      if (u + 2 < 192) LOADB(u + 2);
      LGKM0();
      BAR();
    }
    // ---- epilogue for tile (bm, bn): per-wave LDS re-tile, coalesced stores ----
    float bias[8];
#pragma unroll
    for (int nt = 0; nt < 8; ++nt) bias[nt] = bq[bn * 128 + nt * 16 + jlo];
    if (bn < 8) {  // q or k: token-major rows, 128B-contiguous stores
#pragma unroll
      for (int mt = 0; mt < 2; ++mt)
#pragma unroll
        for (int nt = 0; nt < 8; ++nt)
#pragma unroll
          for (int r = 0; r < 4; ++r)
            Cw[(mt * 16 + g * 4 + r) * 136 + nt * 16 + jlo] =
                (f16)(acc[mt][nt][r] + bias[nt]);
      LGKM0();
      f16* const gb = (bn < 4) ? (qk + bn * 128) : (qk + QK_HALF + (bn - 4) * 128);
#pragma unroll
      for (int p = 0; p < 8; ++p) {
        const int lr = (p >> 1) * 8 + (lane >> 3);
        const int ch = (p & 1) * 8 + (lane & 7);
        const int trow = bm * 256 + wave * 32 + lr;
        *(f16x8*)(gb + trow * 512 + ch * 8) = *(const f16x8*)(Cw + lr * 136 + ch * 8);
      }
    } else {  // v: transpose to vt[w][h][d][s], two 64-col halves
      const int w = (bm * 256 + wave * 32) >> 6;
      const int s0 = (wave * 32) & 63;
#pragma unroll
      for (int hf = 0; hf < 2; ++hf) {
#pragma unroll
        for (int n2 = 0; n2 < 4; ++n2) {
          const int nt = hf * 4 + n2;
#pragma unroll
          for (int mt = 0; mt < 2; ++mt) {
            f16x4 pk = { (f16)(acc[mt][nt][0] + bias[nt]), (f16)(acc[mt][nt][1] + bias[nt]),
                         (f16)(acc[mt][nt][2] + bias[nt]), (f16)(acc[mt][nt][3] + bias[nt]) };
            *(f16x4*)(Cw + (n2 * 16 + jlo) * 48 + mt * 16 + g * 4) = pk;
          }
        }
        LGKM0();
#pragma unroll
        for (int p = 0; p < 4; ++p) {
          const int cl = p * 16 + (lane >> 2);
          const int ch = lane & 3;
          const int n = (bn - 8) * 128 + hf * 64 + cl;
          const int h = n >> 5, d = n & 31;
          *(f16x8*)(vt + ((w * 16 + h) * 32 + d) * 64 + s0 + ch * 8) =
              *(const f16x8*)(Cw + cl * 48 + ch * 8);
        }
      }
    }
#pragma unroll
    for (int mt = 0; mt < 2; ++mt)
#pragma unroll
      for (int nt = 0; nt < 8; ++nt)
        acc[mt][nt] = (f32x4){0.f, 0.f, 0.f, 0.f};
  }
#undef LOADB
#undef WRITEB
}

// ---------------------------------------------------------------------------
// Kernel 2: per-window attention (verified structure; normal stores).
// ---------------------------------------------------------------------------
__global__ __launch_bounds__(256) void k_attn(const f16* __restrict__ qk,
                                              const f16* __restrict__ vt,
                                              f16* __restrict__ ao) {
  __shared__ f16 P[4][64 * 72];
  const int w = blockIdx.x;
  const int widx = w & 63;
  const bool er = (widx >> 3) == 7;
  const bool ec = (widx & 7) == 7;
  const int tid = threadIdx.x;
  const int lane = tid & 63, wave = tid >> 6;
  const int jlo = lane & 15, g = lane >> 4;
  const int tb = w * 64;
  f16* Pw = P[wave];
  const float scale = 0.17677669529663687f;

#pragma unroll 1
  for (int hh = 0; hh < 4; ++hh) {
    const int h = wave * 4 + hh;
    f16x8 qa[4], kb[4];
#pragma unroll
    for (int mt = 0; mt < 4; ++mt)
      qa[mt] = *(const f16x8*)(qk + (tb + mt * 16 + jlo) * 512 + h * 32 + g * 8);
#pragma unroll
    for (int nt = 0; nt < 4; ++nt)
      kb[nt] = *(const f16x8*)(qk + QK_HALF + (tb + nt * 16 + jlo) * 512 + h * 32 + g * 8);
    f32x4 sc[4][4] = {};
#pragma unroll
    for (int mt = 0; mt < 4; ++mt)
#pragma unroll
      for (int nt = 0; nt < 4; ++nt)
        sc[mt][nt] = MFMA16(qa[mt], kb[nt], sc[mt][nt]);

    int gj[4];
#pragma unroll
    for (int nt = 0; nt < 4; ++nt) {
      int j = nt * 16 + jlo;
      gj[nt] = ((er && ((j >> 3) >= 4)) ? 2 : 0) | ((ec && ((j & 7) >= 4)) ? 1 : 0);
    }
    float rinv[4][4];
#pragma unroll
    for (int mt = 0; mt < 4; ++mt) {
#pragma unroll
      for (int r = 0; r < 4; ++r) {
        const int i = mt * 16 + g * 4 + r;
        const int gi = ((er && ((i >> 3) >= 4)) ? 2 : 0) | ((ec && ((i & 7) >= 4)) ? 1 : 0);
        float v0 = (gi == gj[0]) ? sc[mt][0][r] * scale : -1e9f;
        float v1 = (gi == gj[1]) ? sc[mt][1][r] * scale : -1e9f;
        float v2 = (gi == gj[2]) ? sc[mt][2][r] * scale : -1e9f;
        float v3 = (gi == gj[3]) ? sc[mt][3][r] * scale : -1e9f;
        float m = fmaxf(fmaxf(v0, v1), fmaxf(v2, v3));
        m = fmaxf(m, __shfl_xor(m, 1));
        m = fmaxf(m, __shfl_xor(m, 2));
        m = fmaxf(m, __shfl_xor(m, 4));
        m = fmaxf(m, __shfl_xor(m, 8));
        float p0 = __expf(v0 - m), p1 = __expf(v1 - m);
        float p2 = __expf(v2 - m), p3 = __expf(v3 - m);
        float s = p0 + p1 + p2 + p3;
        s += __shfl_xor(s, 1);
        s += __shfl_xor(s, 2);
        s += __shfl_xor(s, 4);
        s += __shfl_xor(s, 8);
        rinv[mt][r] = 1.0f / s;
        sc[mt][0][r] = p0; sc[mt][1][r] = p1; sc[mt][2][r] = p2; sc[mt][3][r] = p3;
      }
    }
#pragma unroll
    for (int mt = 0; mt < 4; ++mt)
#pragma unroll
      for (int nt = 0; nt < 4; ++nt)
#pragma unroll
        for (int r = 0; r < 4; ++r)
          Pw[(mt * 16 + g * 4 + r) * 72 + nt * 16 + jlo] = (f16)sc[mt][nt][r];
    asm volatile("s_waitcnt lgkmcnt(0)" ::: "memory");

    f32x4 o[4][2] = {};
#pragma unroll
    for (int ks = 0; ks < 2; ++ks) {
      f16x8 pa[4], vb[2];
#pragma unroll
      for (int mt = 0; mt < 4; ++mt)
        pa[mt] = *(const f16x8*)((const char*)Pw + (mt * 16 + jlo) * 144 + ks * 64 + g * 16);
#pragma unroll
      for (int nt = 0; nt < 2; ++nt)
        vb[nt] = *(const f16x8*)(vt + ((w * 16 + h) * 32 + nt * 16 + jlo) * 64 + ks * 32 + g * 8);
#pragma unroll
      for (int mt = 0; mt < 4; ++mt)
#pragma unroll
        for (int nt = 0; nt < 2; ++nt)
          o[mt][nt] = MFMA16(pa[mt], vb[nt], o[mt][nt]);
    }
#pragma unroll
    for (int mt = 0; mt < 4; ++mt)
#pragma unroll
      for (int nt = 0; nt < 2; ++nt)
#pragma unroll
        for (int r = 0; r < 4; ++r)
          Pw[(mt * 16 + g * 4 + r) * 40 + nt * 16 + jlo] =
              (f16)(o[mt][nt][r] * rinv[mt][r]);
    f16* arow = ao + (tb + lane) * 512 + h * 32;
#pragma unroll
    for (int c = 0; c < 4; ++c)
      *(f16x8*)(arow + c * 8) = *(const f16x8*)(Pw + lane * 40 + c * 8);
  }
}

// ---------------------------------------------------------------------------
// Kernel 3: output projection, A(ao)-in-registers, scatter via tok2patch (NT).
// ---------------------------------------------------------------------------
__global__ __launch_bounds__(512, 2) void k_out(const f16* __restrict__ ao,
                                                const float* __restrict__ wo,
                                                const float* __restrict__ bo,
                                                float* __restrict__ out) {
  __shared__ __align__(16) char smem[86016];  // B0|B1 + 8x8704B Cw (32x68 f32)
  f16* const B0 = (f16*)smem;
  f16* const B1 = (f16*)(smem + 8192);

  const int tid = threadIdx.x;
  const int lane = tid & 63, wave = tid >> 6;
  const int jlo = lane & 15, g = lane >> 4;
  const int bm = blockIdx.x;  // 256 blocks

  const int nl = tid >> 2, kq = tid & 3;
  const int bslot = (kq ^ ((nl >> 1) & 3)) * 8;

  // A-frags straight from ao (f16, contiguous)
  const f16* const a0 = ao + (bm * 256 + wave * 32 + jlo) * 512 + g * 8;
  const f16* const a1 = a0 + 16 * 512;
  f16x8 af[2][16];
#pragma unroll
  for (int ks = 0; ks < 16; ++ks) {
    af[0][ks] = *(const f16x8*)(a0 + ks * 32);
    af[1][ks] = *(const f16x8*)(a1 + ks * 32);
  }

  f32x4 acc[2][8] = {};
  float4 rb[2];
#define LOADB(U2)                                                         \
  do {                                                                    \
    const int bn2_ = (U2) >> 4, k2_ = ((U2) & 15) * 32;                   \
    const float* bs_ = wo + (bn2_ * 128 + nl) * 512 + k2_ + kq * 8;       \
    rb[0] = *(const float4*)(bs_); rb[1] = *(const float4*)(bs_ + 4);     \
  } while (0)
#define WRITEB(Bp) do { *(f16x8*)((Bp) + nl * 32 + bslot) = cvt8(rb[0], rb[1]); } while (0)

  LOADB(0);
  SCHEDBAR();
  VMCNT0();
  WRITEB(B0);
  LOADB(1);
  LGKM0();
  BAR();

#pragma unroll 1
  for (int bn = 0; bn < 4; ++bn) {
    float* const Cw = (float*)(smem + 16384 + wave * 8704);
#pragma unroll
    for (int ks = 0; ks < 16; ++ks) {
      const int u = bn * 16 + ks;
      f16* const Bc = (u & 1) ? B1 : B0;
      f16* const Bn = (u & 1) ? B0 : B1;
      f16x8 bf[8];
#pragma unroll
      for (int nt = 0; nt < 8; ++nt) {
        const int n = nt * 16 + jlo;
        bf[nt] = *(const f16x8*)(Bc + n * 32 + ((g ^ ((n >> 1) & 3)) * 8));
      }
      __builtin_amdgcn_s_setprio(1);
#pragma unroll
      for (int mt = 0; mt < 2; ++mt)
#pragma unroll
        for (int nt = 0; nt < 8; ++nt)
          acc[mt][nt] = MFMA16(af[mt][ks], bf[nt], acc[mt][nt]);
      __builtin_amdgcn_s_setprio(0);
      VMCNT0();
      if (u + 1 < 64) WRITEB(Bn);
      SCHEDBAR();
      if (u + 2 < 64) LOADB(u + 2);
      LGKM0();
      BAR();
    }
    // epilogue: two 64-col halves, fp32 scatter rows via tok2patch (NT)
#pragma unroll
    for (int hf = 0; hf < 2; ++hf) {
#pragma unroll
      for (int n2 = 0; n2 < 4; ++n2) {
        const int nt = hf * 4 + n2;
        const float bias = bo[bn * 128 + nt * 16 + jlo];
#pragma unroll
        for (int mt = 0; mt < 2; ++mt)
#pragma unroll
          for (int r = 0; r < 4; ++r)
            Cw[(mt * 16 + g * 4 + r) * 68 + n2 * 16 + jlo] = acc[mt][nt][r] + bias;
      }
      LGKM0();
#pragma unroll
      for (int p = 0; p < 8; ++p) {
        const int lr = (p >> 1) * 8 + (lane >> 3);
        const int ch = (p & 1) * 8 + (lane & 7);
        const int trow = bm * 256 + wave * 32 + lr;
        nts4f(*(const f32x4*)(Cw + lr * 68 + ch * 4),
              out + tok2patch(trow) + bn * 128 + hf * 64 + ch * 4);
      }
      LGKM0();  // reads done before next half's writes (same-wave DS in order)
    }
#pragma unroll
    for (int mt = 0; mt < 2; ++mt)
#pragma unroll
      for (int nt = 0; nt < 8; ++nt)
        acc[mt][nt] = (f32x4){0.f, 0.f, 0.f, 0.f};
  }
#undef LOADB
#undef WRITEB
}

extern "C" void kernel_launch(void* const* d_in, const int* in_sizes, int n_in,
                              void* d_out, int out_size, void* d_ws, size_t ws_size,
                              hipStream_t stream) {
  const float* x  = (const float*)d_in[0];
  const float* wq = (const float*)d_in[1];
  const float* bq = (const float*)d_in[2];
  const float* wo = (const float*)d_in[3];
  const float* bo = (const float*)d_in[4];
  float* out = (float*)d_out;

  f16* qk = (f16*)d_out;                        // q|k overlay (128 MiB)
  f16* ao = (f16*)d_ws;                         // attention output (64 MiB)
  f16* vt = (f16*)((char*)d_ws + (64u << 20));  // V transposed (64 MiB)

  k_qkv<<<dim3(256), 512, 0, stream>>>(x, wq, bq, qk, vt);
  k_attn<<<dim3(1024), 256, 0, stream>>>(qk, vt, ao);
  k_out<<<dim3(256), 512, 0, stream>>>(ao, wo, bo, out);
}